// Round 7
// baseline (98.801 us; speedup 1.0000x reference)
//
#include <hip/hip_runtime.h>
#include <hip/hip_bf16.h>

#define IN_F   4096
#define OUT_F  4096
#define BATCH  256

#define BN 16          // weight rows (out-features) per block
#define BK 64          // K per step
#define NK (IN_F / BK) // 64 k-steps

typedef __attribute__((ext_vector_type(8))) short shortx8;    // 8 bf16
typedef __attribute__((ext_vector_type(4))) float floatx4;
typedef __attribute__((ext_vector_type(4))) unsigned short ushortx4;

typedef __attribute__((address_space(1))) const void GlbV;
typedef __attribute__((address_space(3))) void LdsV;

static __device__ __forceinline__ ushort f2bf(float f) {
    union { float f; unsigned int u; } v; v.f = f;
    unsigned int u = v.u;
    u += 0x7FFFu + ((u >> 16) & 1u);   // RNE
    return (ushort)(u >> 16);
}

static __device__ __forceinline__ float softplus_fast(float x) {
    return (x > 15.f) ? x : __logf(1.f + __expf(x));
}

#define KL_C0 (-2.80258509299f)   // log(0.1) - 0.5  (prior_sigma=0.1, prior_mu=0: spec constants)

// sample 4 weights -> bf16 LDS write (8B, pre-swizzled dst), accumulate KL
static __device__ __forceinline__ void sample4(floatx4 m4, floatx4 r4, floatx4 e4,
                                               char* dst, float& kl) {
    ushort w[4];
#pragma unroll
    for (int j = 0; j < 4; ++j) {
        float sig = softplus_fast(r4[j]);
        w[j] = f2bf(fmaf(sig, e4[j], m4[j]));
        kl += fmaf(50.f, fmaf(sig, sig, m4[j] * m4[j]), KL_C0 - __logf(sig));
    }
    ushortx4 pk = { w[0], w[1], w[2], w[3] };
    *(ushortx4*)dst = pk;
}

// ---------------- Kernel A: x f32 -> bf16 -----------------------------------
__global__ __launch_bounds__(256) void xconv_kernel(
    const float* __restrict__ x, ushort* __restrict__ xb)
{
    int i = blockIdx.x * blockDim.x + threadIdx.x;   // over (BATCH*IN_F)/4
    float4 v = ((const float4*)x)[i];
    ushortx4 o = { f2bf(v.x), f2bf(v.y), f2bf(v.z), f2bf(v.w) };
    ((ushortx4*)xb)[i] = o;
}

// ---------------- Kernel B: fused sample + KL + GEMM + bias ------------------
// Each block owns out-feature rows n0..n0+15 for ALL 256 batch rows:
// params (mu/rho/eps) for those rows are read exactly once (NT), sampled to
// bf16 in-block, and fed straight into MFMA. x (bf16, 2 MB) staged per k-step
// via global_load_lds, double-buffered. One barrier per k-step; next-step
// loads issued before current-step compute (latency hidden under MFMA+VALU).
// LDS XOR swizzle (granule16 ^= row&7) applied pre-swizzled on the source for
// A (gload_lds is linear) and on the ds_write addr for B; reads use same XOR.
__global__ __launch_bounds__(256) void fused_kernel(
    const ushort* __restrict__ xb,
    const float* __restrict__ mu, const float* __restrict__ rho,
    const float* __restrict__ eps,
    const float* __restrict__ bias_mu, const float* __restrict__ bias_rho,
    const float* __restrict__ eps_b,
    float* __restrict__ C, float* __restrict__ partials)
{
    // A dbuf: 2 x (256 rows x 64 k) bf16 = 64 KB; B dbuf: 2 x (16 x 64) = 4 KB
    __shared__ ushort lds[2 * 256 * 64 + 2 * 16 * 64];
    char* const L = (char*)lds;
    const int A_OFF = 0, A_SZ = 32768, B_OFF = 65536, B_SZ = 2048;

    const int tid  = threadIdx.x;
    const int w    = tid >> 6;
    const int lane = tid & 63;
    const int lr   = lane & 15;
    const int hi   = lane >> 4;
    const int lx   = lr & 7;
    const int n0   = blockIdx.x * BN;

    // ---- A staging addressing: 8 gload_lds per wave per step ----
    // call c: rows w*64 + c*8 + (lane>>3), lane granule (tid&7)^(row&7)
    const int arow = w * 64 + ((tid >> 3) & 7);
    const int ag   = (tid & 7) ^ ((tid >> 3) & 7);
    const ushort* Ag = xb + (size_t)arow * IN_F + ag * 8;
    const int AdstW  = w * 8192;   // wave-uniform dest base (+ c*1024)

    // ---- B param addressing: thread -> (row=tid>>4, k4=(tid&15)*4) ----
    const int prow = tid >> 4;
    const int pk4  = (tid & 15) * 4;
    const float* muP  = mu  + (size_t)(n0 + prow) * IN_F + pk4;
    const float* rhoP = rho + (size_t)(n0 + prow) * IN_F + pk4;
    const float* epsP = eps + (size_t)(n0 + prow) * IN_F + pk4;
    const int bq   = (tid & 15) >> 1;
    const int BwrOff = prow * 128 + ((bq ^ (prow & 7)) << 4) + (tid & 1) * 8;

    floatx4 acc[4] = {};
    float kl = 0.f;

    // ---- prologue: t = 0 ----
    {
        floatx4 Pm = __builtin_nontemporal_load((const floatx4*)muP);
        floatx4 Pr = __builtin_nontemporal_load((const floatx4*)rhoP);
        floatx4 Pe = __builtin_nontemporal_load((const floatx4*)epsP);
#pragma unroll
        for (int c = 0; c < 8; ++c)
            __builtin_amdgcn_global_load_lds((GlbV*)(Ag + c * 8 * IN_F),
                                             (LdsV*)(L + A_OFF + AdstW + c * 1024), 16, 0, 0);
        sample4(Pm, Pr, Pe, L + B_OFF + BwrOff, kl);
    }
    __syncthreads();

    int cur = 0;
    for (int t = 0; t < NK; ++t) {
        const int nxt = cur ^ 1;
        floatx4 Qm, Qr, Qe;
        if (t + 1 < NK) {
            const int ko = (t + 1) * BK;
            Qm = __builtin_nontemporal_load((const floatx4*)(muP + ko));
            Qr = __builtin_nontemporal_load((const floatx4*)(rhoP + ko));
            Qe = __builtin_nontemporal_load((const floatx4*)(epsP + ko));
#pragma unroll
            for (int c = 0; c < 8; ++c)
                __builtin_amdgcn_global_load_lds((GlbV*)(Ag + c * 8 * IN_F + ko),
                                                 (LdsV*)(L + A_OFF + nxt * A_SZ + AdstW + c * 1024), 16, 0, 0);
        }
        // ---- compute from buffers[cur] ----
        char* Ab = L + A_OFF + cur * A_SZ;
        char* Bb = L + B_OFF + cur * B_SZ;
#pragma unroll
        for (int s = 0; s < 2; ++s) {
            const int q = s * 4 + hi;
            const int cs = ((q ^ lx) << 4);
            shortx8 bfr = *(const shortx8*)(Bb + lr * 128 + cs);
#pragma unroll
            for (int mt = 0; mt < 4; ++mt) {
                const int r = w * 64 + mt * 16 + lr;
                shortx8 af = *(const shortx8*)(Ab + r * 128 + cs);
                acc[mt] = __builtin_amdgcn_mfma_f32_16x16x32_bf16(af, bfr, acc[mt], 0, 0, 0);
            }
        }
        if (t + 1 < NK)
            sample4(Qm, Qr, Qe, L + B_OFF + nxt * B_SZ + BwrOff, kl);
        __syncthreads();   // drains gload_lds (vmcnt0) + ds_writes; flips safe
        cur = nxt;
    }

    // ---- epilogue: bias sample + C store ----
    {
        const int n = n0 + lr;
        const float bv = fmaf(softplus_fast(bias_rho[n]), eps_b[n], bias_mu[n]);
#pragma unroll
        for (int mt = 0; mt < 4; ++mt) {
            const int mbase = w * 64 + mt * 16 + hi * 4;
#pragma unroll
            for (int q2 = 0; q2 < 4; ++q2)
                C[(size_t)(mbase + q2) * OUT_F + n] = acc[mt][q2] + bv;
        }
    }

    // ---- KL: wave reduce then block reduce -> one partial per block ----
#pragma unroll
    for (int off = 32; off; off >>= 1) kl += __shfl_down(kl, off);
    __shared__ float wsum[4];
    if (lane == 0) wsum[w] = kl;
    __syncthreads();
    if (tid == 0)
        partials[blockIdx.x] = wsum[0] + wsum[1] + wsum[2] + wsum[3];
}

// ---------------- Kernel C: final KL reduction (256 partials) ----------------
__global__ __launch_bounds__(256) void kl_reduce_kernel(
    const float* __restrict__ partials, float* __restrict__ kl_out)
{
    float s = partials[threadIdx.x];
#pragma unroll
    for (int off = 32; off; off >>= 1) s += __shfl_down(s, off);
    __shared__ float wsum[4];
    if ((threadIdx.x & 63) == 0) wsum[threadIdx.x >> 6] = s;
    __syncthreads();
    if (threadIdx.x == 0)
        *kl_out = wsum[0] + wsum[1] + wsum[2] + wsum[3];
}

extern "C" void kernel_launch(void* const* d_in, const int* in_sizes, int n_in,
                              void* d_out, int out_size, void* d_ws, size_t ws_size,
                              hipStream_t stream) {
    const float* x     = (const float*)d_in[0];
    const float* w_mu  = (const float*)d_in[1];
    const float* w_rho = (const float*)d_in[2];
    const float* b_mu  = (const float*)d_in[3];
    const float* b_rho = (const float*)d_in[4];
    const float* eps_w = (const float*)d_in[5];
    const float* eps_b = (const float*)d_in[6];
    // d_in[7]=prior_mu (zeros), d_in[8]=prior_sigma (0.1): folded constants.

    float* out = (float*)d_out;
    const size_t KL_IDX = (size_t)BATCH * OUT_F;

    ushort* x_bf     = (ushort*)d_ws;                                   // 2 MB
    float*  partials = (float*)((char*)d_ws + (size_t)BATCH * IN_F * 2); // 1 KB

    // x -> bf16
    xconv_kernel<<<(BATCH * IN_F / 4) / 256, 256, 0, stream>>>(x, x_bf);
    // fused sample + KL + GEMM + bias
    fused_kernel<<<OUT_F / BN, 256, 0, stream>>>(
        x_bf, w_mu, w_rho, eps_w, b_mu, b_rho, eps_b, out, partials);
    // final KL
    kl_reduce_kernel<<<1, 256, 0, stream>>>(partials, out + KL_IDX);
}